// Round 11
// baseline (202.298 us; speedup 1.0000x reference)
//
#include <hip/hip_runtime.h>
#include <math.h>

#define S_LEN 2048
#define DM 768
#define NHEAD 12
#define DHEAD 64
#define HALF_W 64

typedef _Float16 half8 __attribute__((ext_vector_type(8)));
typedef _Float16 half4_t __attribute__((ext_vector_type(4)));
typedef float floatx4 __attribute__((ext_vector_type(4)));

// ---- async global->LDS, 16B per lane (dest = wave-uniform base + lane*16) ----
typedef const __attribute__((address_space(1))) unsigned int* gas_ptr;
typedef __attribute__((address_space(3))) unsigned int* las_ptr;
__device__ __forceinline__ void gld_lds16(const void* g, void* l) {
  __builtin_amdgcn_global_load_lds((gas_ptr)g, (las_ptr)l, 16, 0, 0);
}

// ---------------- weight prep: cvt+transpose W[k][n] fp32 -> Wt[n][k] f16 ----------------
__global__ __launch_bounds__(256)
void prep_w_kernel(const float* __restrict__ Wq, const float* __restrict__ Wk,
                   const float* __restrict__ Wv, const float* __restrict__ Wo,
                   _Float16* __restrict__ Tq, _Float16* __restrict__ Tk,
                   _Float16* __restrict__ Tv, _Float16* __restrict__ To) {
  __shared__ float t[64][65];
  int b = blockIdx.x;
  int z = b / 144, rem = b % 144;
  const float* W = z == 0 ? Wq : z == 1 ? Wk : z == 2 ? Wv : Wo;
  _Float16* T = z == 0 ? Tq : z == 1 ? Tk : z == 2 ? Tv : To;
  int n0 = (rem % 12) * 64, k0 = (rem / 12) * 64;
  int tx = threadIdx.x & 15, ty = threadIdx.x >> 4;
#pragma unroll
  for (int i = 0; i < 4; ++i) {
    int row = ty + i * 16;
    float4 v = *(const float4*)(W + (size_t)(k0 + row) * DM + n0 + tx * 4);
    t[row][tx * 4 + 0] = v.x; t[row][tx * 4 + 1] = v.y;
    t[row][tx * 4 + 2] = v.z; t[row][tx * 4 + 3] = v.w;
  }
  __syncthreads();
#pragma unroll
  for (int i = 0; i < 4; ++i) {
    int nn = ty + i * 16, kk = tx * 4;
    half4_t h = {(_Float16)t[kk + 0][nn], (_Float16)t[kk + 1][nn],
                 (_Float16)t[kk + 2][nn], (_Float16)t[kk + 3][nn]};
    *(half4_t*)(T + (size_t)(n0 + nn) * DM + k0 + kk) = h;
  }
}

// ---------------- QKV GEMM: LDS-FREE direct-MFMA ----------------
// Both operands are k-major in global (A[m][k] fp32, Wt[n][k] f16) -> fragments
// load directly per-lane. Zero barriers; compiler pipelines loads across K with
// partial vmcnt (AITER pattern). Reuse via L1/L2 (XCD-ownership grid kept).
#define GBM 64
#define GBN 64

__global__ __launch_bounds__(256, 4)
void gemm_qkv_kernel(const float* __restrict__ A0, const float* __restrict__ A1,
                     const float* __restrict__ A2, const _Float16* __restrict__ W0,
                     const _Float16* __restrict__ W1, const _Float16* __restrict__ W2,
                     const float* __restrict__ b0, const float* __restrict__ b1,
                     const float* __restrict__ b2, _Float16* __restrict__ Q,
                     _Float16* __restrict__ K, _Float16* __restrict__ Vt) {
  // 1152 blocks = 8 XCDs x 12 panels x 12 n-tiles
  const int bid = blockIdx.x;
  const int xcd = bid & 7;
  const int li = bid >> 3;
  const int panel = xcd * 12 + li / 12;   // 0..95 = z*32 + m-block
  const int nb = li % 12;
  const int z = panel >> 5;
  const int m0 = (panel & 31) * GBM;
  const int n0 = nb * GBN;
  const float* A = z == 0 ? A0 : z == 1 ? A1 : A2;
  const _Float16* Wt = z == 0 ? W0 : z == 1 ? W1 : W2;
  const float* bias = z == 0 ? b0 : z == 1 ? b1 : b2;

  const int tid = threadIdx.x;
  const int lane = tid & 63;
  const int w = tid >> 6;
  const int lr = lane & 15;
  const int lq = lane >> 4;
  const int wm = w >> 1, wn = w & 1;

  const float* Abase = A + (size_t)(m0 + wm * 32 + lr) * DM + lq * 8;
  const _Float16* Bbase = Wt + (size_t)(n0 + wn * 32 + lr) * DM + lq * 8;

  floatx4 acc[2][2] = {};

  for (int k0 = 0; k0 < DM; k0 += 64) {
    half8 af[2][2], bf[2][2];
#pragma unroll
    for (int kh = 0; kh < 2; ++kh)
#pragma unroll
      for (int mt = 0; mt < 2; ++mt) {
        const float* p = Abase + (size_t)mt * 16 * DM + k0 + kh * 32;
        float4 f0 = *(const float4*)p;
        float4 f1 = *(const float4*)(p + 4);
        af[kh][mt] = half8{(_Float16)f0.x, (_Float16)f0.y, (_Float16)f0.z, (_Float16)f0.w,
                           (_Float16)f1.x, (_Float16)f1.y, (_Float16)f1.z, (_Float16)f1.w};
      }
#pragma unroll
    for (int kh = 0; kh < 2; ++kh)
#pragma unroll
      for (int nt = 0; nt < 2; ++nt)
        bf[kh][nt] = *(const half8*)(Bbase + (size_t)nt * 16 * DM + k0 + kh * 32);
#pragma unroll
    for (int kh = 0; kh < 2; ++kh)
#pragma unroll
      for (int mt = 0; mt < 2; ++mt)
#pragma unroll
        for (int nt = 0; nt < 2; ++nt)
          acc[mt][nt] = __builtin_amdgcn_mfma_f32_16x16x32_f16(af[kh][mt], bf[kh][nt], acc[mt][nt], 0, 0, 0);
  }

  const int lq4 = lq * 4;
#pragma unroll
  for (int mt = 0; mt < 2; ++mt) {
    int row0 = m0 + wm * 32 + mt * 16 + lq4;
#pragma unroll
    for (int nt = 0; nt < 2; ++nt) {
      int col = n0 + wn * 32 + nt * 16 + lr;
      float bv = bias[col];
      if (z == 2) {  // V proj: write V^T[d=col][s=row] (fused transpose)
        half4_t o = {(_Float16)(acc[mt][nt][0] + bv), (_Float16)(acc[mt][nt][1] + bv),
                     (_Float16)(acc[mt][nt][2] + bv), (_Float16)(acc[mt][nt][3] + bv)};
        *(half4_t*)(Vt + (size_t)col * S_LEN + row0) = o;
      } else {
        _Float16* H = z == 0 ? Q : K;
#pragma unroll
        for (int rr = 0; rr < 4; ++rr)
          H[(size_t)(row0 + rr) * DM + col] = (_Float16)(acc[mt][nt][rr] + bv);
      }
    }
  }
}

// ---------------- Wo GEMM: LDS-free direct-MFMA, f16 A (ctx), fp32 out ----------------
__global__ __launch_bounds__(256, 4)
void gemm_out_kernel(const _Float16* __restrict__ A, const _Float16* __restrict__ Wt,
                     const float* __restrict__ bias, float* __restrict__ C) {
  // 384 blocks = 8 XCDs x 4 m-panels x 12 n-tiles
  const int bid = blockIdx.x;
  const int xcd = bid & 7;
  const int li = bid >> 3;
  const int m0 = (xcd * 4 + li / 12) * GBM;
  const int n0 = (li % 12) * GBN;
  const int tid = threadIdx.x;
  const int lane = tid & 63;
  const int w = tid >> 6;
  const int lr = lane & 15;
  const int lq = lane >> 4;
  const int wm = w >> 1, wn = w & 1;

  const _Float16* Abase = A + (size_t)(m0 + wm * 32 + lr) * DM + lq * 8;
  const _Float16* Bbase = Wt + (size_t)(n0 + wn * 32 + lr) * DM + lq * 8;

  floatx4 acc[2][2] = {};

  for (int k0 = 0; k0 < DM; k0 += 64) {
    half8 af[2][2], bf[2][2];
#pragma unroll
    for (int kh = 0; kh < 2; ++kh)
#pragma unroll
      for (int mt = 0; mt < 2; ++mt)
        af[kh][mt] = *(const half8*)(Abase + (size_t)mt * 16 * DM + k0 + kh * 32);
#pragma unroll
    for (int kh = 0; kh < 2; ++kh)
#pragma unroll
      for (int nt = 0; nt < 2; ++nt)
        bf[kh][nt] = *(const half8*)(Bbase + (size_t)nt * 16 * DM + k0 + kh * 32);
#pragma unroll
    for (int kh = 0; kh < 2; ++kh)
#pragma unroll
      for (int mt = 0; mt < 2; ++mt)
#pragma unroll
        for (int nt = 0; nt < 2; ++nt)
          acc[mt][nt] = __builtin_amdgcn_mfma_f32_16x16x32_f16(af[kh][mt], bf[kh][nt], acc[mt][nt], 0, 0, 0);
  }

#pragma unroll
  for (int mt = 0; mt < 2; ++mt) {
    int row0 = m0 + wm * 32 + mt * 16 + lq * 4;
#pragma unroll
    for (int nt = 0; nt < 2; ++nt) {
      int col = n0 + wn * 32 + nt * 16 + lr;
      float bv = bias[col];
#pragma unroll
      for (int rr = 0; rr < 4; ++rr)
        C[(size_t)(row0 + rr) * DM + col] = acc[mt][nt][rr] + bv;
    }
  }
}

// ---------------- MFMA sliding-window attention, in-register softmax (R10) ----------------
#define ATQ 32

__global__ __launch_bounds__(256, 3)
void swattn_mfma_kernel(const _Float16* __restrict__ qh, const _Float16* __restrict__ kh,
                        const _Float16* __restrict__ vt, _Float16* __restrict__ ctx) {
  __shared__ __align__(16) _Float16 Ks[160 * 64];   // 20 KB
  __shared__ __align__(16) _Float16 Vs[64 * 168];   // 21 KB
  __shared__ __align__(16) _Float16 QP[32 * 168];   // 10.5 KB: Qs then Pbuf
  __shared__ float red[4][32];

  const int tid = threadIdx.x;
  const int lane = tid & 63, w = tid >> 6;
  const int lr = lane & 15, lq = lane >> 4;
  const int bid = blockIdx.x;
  const int x = bid & 7, mid = (bid >> 3) & 7, h = bid >> 6;
  const int s0 = (x * 8 + mid) * ATQ;
  const int wb = tid & 192;

  {
    int r = tid >> 3, j = tid & 7, jg = j ^ (r & 7);
    gld_lds16(qh + (size_t)(s0 + r) * DM + h * DHEAD + jg * 8, &QP[wb * 8]);
  }
#pragma unroll
  for (int i = 0; i < 5; ++i) {
    int c = i * 256 + tid;
    int r = c >> 3, j = c & 7, jg = j ^ (r & 7);
    int pos = s0 - HALF_W + r;
    pos = pos < 0 ? 0 : (pos > S_LEN - 1 ? S_LEN - 1 : pos);
    gld_lds16(kh + (size_t)pos * DM + h * DHEAD + jg * 8, &Ks[(i * 256 + wb) * 8]);
  }
#pragma unroll
  for (int i = 0; i < 6; ++i) {
    int c = i * 256 + tid;
    if (c < 1344) {
      int r = c / 21, j = c % 21;
      int cb = s0 - HALF_W + j * 8;
      cb = cb < 0 ? 0 : (cb > S_LEN - 8 ? S_LEN - 8 : cb);
      gld_lds16(vt + (size_t)(h * DHEAD + r) * S_LEN + cb, &Vs[(i * 256 + wb) * 8]);
    }
  }
  __syncthreads();

  const int qt = w & 1, ph = w >> 1;
  floatx4 sc[5];
  {
    half8 aq[2];
#pragma unroll
    for (int k2 = 0; k2 < 2; ++k2) {
      int r = qt * 16 + lr, j = (k2 * 4 + lq) ^ (r & 7);
      aq[k2] = *(const half8*)&QP[r * DHEAD + j * 8];
    }
#pragma unroll
    for (int t = 0; t < 5; ++t) {
      int pt = ph * 5 + t;
      floatx4 a = {};
#pragma unroll
      for (int k2 = 0; k2 < 2; ++k2) {
        int r = pt * 16 + lr, j = (k2 * 4 + lq) ^ (r & 7);
        half8 bk = *(const half8*)&Ks[r * DHEAD + j * 8];
        a = __builtin_amdgcn_mfma_f32_16x16x32_f16(aq[k2], bk, a, 0, 0, 0);
      }
      sc[t] = a;
    }
  }

  const int qbase = qt * 16 + lq * 4;
  float m4[4] = {-1e30f, -1e30f, -1e30f, -1e30f};
#pragma unroll
  for (int t = 0; t < 5; ++t) {
    int p = (ph * 5 + t) * 16 + lr;
    int g = s0 - HALF_W + p;
#pragma unroll
    for (int rr = 0; rr < 4; ++rr) {
      int q = qbase + rr;
      bool ok = (p >= q) && (p <= q + 128) && (g >= 0) && (g < S_LEN);
      float v = ok ? sc[t][rr] * 0.125f : -1e30f;
      sc[t][rr] = v;
      m4[rr] = fmaxf(m4[rr], v);
    }
  }
#pragma unroll
  for (int off = 1; off <= 8; off <<= 1)
#pragma unroll
    for (int rr = 0; rr < 4; ++rr) m4[rr] = fmaxf(m4[rr], __shfl_xor(m4[rr], off, 64));
  if (lr == 0)
#pragma unroll
    for (int rr = 0; rr < 4; ++rr) red[ph][qbase + rr] = m4[rr];
  __syncthreads();

  float ss[4] = {0.f, 0.f, 0.f, 0.f};
  float mm[4];
#pragma unroll
  for (int rr = 0; rr < 4; ++rr)
    mm[rr] = fmaxf(red[0][qbase + rr], red[1][qbase + rr]);
#pragma unroll
  for (int t = 0; t < 5; ++t)
#pragma unroll
    for (int rr = 0; rr < 4; ++rr) {
      float e = __expf(sc[t][rr] - mm[rr]);
      sc[t][rr] = e;
      ss[rr] += e;
    }
#pragma unroll
  for (int off = 1; off <= 8; off <<= 1)
#pragma unroll
    for (int rr = 0; rr < 4; ++rr) ss[rr] += __shfl_xor(ss[rr], off, 64);
  if (lr == 0)
#pragma unroll
    for (int rr = 0; rr < 4; ++rr) red[2 + ph][qbase + rr] = ss[rr];
  __syncthreads();

#pragma unroll
  for (int rr = 0; rr < 4; ++rr) {
    float inv = 1.f / (red[2][qbase + rr] + red[3][qbase + rr]);
#pragma unroll
    for (int t = 0; t < 5; ++t) {
      int p = (ph * 5 + t) * 16 + lr;
      QP[(qbase + rr) * 168 + p] = (_Float16)(sc[t][rr] * inv);
    }
  }
  __syncthreads();

  {
    const int qt2 = w & 1;
    const int dt0 = (w >> 1) * 2;
    floatx4 a0 = {}, a1 = {};
#pragma unroll
    for (int ks = 0; ks < 5; ++ks) {
      half8 ap = *(const half8*)&QP[(qt2 * 16 + lr) * 168 + ks * 32 + lq * 8];
      half8 bv0 = *(const half8*)&Vs[(dt0 * 16 + lr) * 168 + ks * 32 + lq * 8];
      half8 bv1 = *(const half8*)&Vs[((dt0 + 1) * 16 + lr) * 168 + ks * 32 + lq * 8];
      a0 = __builtin_amdgcn_mfma_f32_16x16x32_f16(ap, bv0, a0, 0, 0, 0);
      a1 = __builtin_amdgcn_mfma_f32_16x16x32_f16(ap, bv1, a1, 0, 0, 0);
    }
#pragma unroll
    for (int rr = 0; rr < 4; ++rr) {
      size_t row = (size_t)(s0 + qt2 * 16 + lq * 4 + rr) * DM + h * DHEAD;
      ctx[row + dt0 * 16 + lr] = (_Float16)a0[rr];
      ctx[row + (dt0 + 1) * 16 + lr] = (_Float16)a1[rr];
    }
  }
}

// ---------------- launch ----------------
extern "C" void kernel_launch(void* const* d_in, const int* in_sizes, int n_in,
                              void* d_out, int out_size, void* d_ws, size_t ws_size,
                              hipStream_t stream) {
  const float* query = (const float*)d_in[0];
  const float* key   = (const float*)d_in[1];
  const float* value = (const float*)d_in[2];
  const float* Wq = (const float*)d_in[3];
  const float* bq = (const float*)d_in[4];
  const float* Wk = (const float*)d_in[5];
  const float* bk = (const float*)d_in[6];
  const float* Wv = (const float*)d_in[7];
  const float* bv = (const float*)d_in[8];
  const float* Wo = (const float*)d_in[9];
  const float* bo = (const float*)d_in[10];
  float* out = (float*)d_out;

  const size_t nel = (size_t)S_LEN * DM;
  const size_t wel = (size_t)DM * DM;
  _Float16* Wtq = (_Float16*)d_ws;
  _Float16* Wtk = Wtq + wel;
  _Float16* Wtv = Wtk + wel;
  _Float16* Wto = Wtv + wel;
  _Float16* qh = Wto + wel;
  _Float16* khb = qh + nel;
  _Float16* Vtg = khb + nel;   // [768][2048] f16
  _Float16* ctxh = Vtg + nel;

  prep_w_kernel<<<dim3(576), 256, 0, stream>>>(Wq, Wk, Wv, Wo, Wtq, Wtk, Wtv, Wto);
  gemm_qkv_kernel<<<dim3(1152), 256, 0, stream>>>(
      query, key, value, Wtq, Wtk, Wtv, bq, bk, bv, qh, khb, Vtg);
  swattn_mfma_kernel<<<dim3((S_LEN / ATQ) * NHEAD), 256, 0, stream>>>(qh, khb, Vtg, ctxh);
  gemm_out_kernel<<<dim3(384), 256, 0, stream>>>(ctxh, Wto, bo, out);
}

// Round 12
// 130.133 us; speedup vs baseline: 1.5545x; 1.5545x over previous
//
#include <hip/hip_runtime.h>
#include <math.h>

#define S_LEN 2048
#define DM 768
#define NHEAD 12
#define DHEAD 64
#define HALF_W 64

typedef _Float16 half8 __attribute__((ext_vector_type(8)));
typedef _Float16 half4_t __attribute__((ext_vector_type(4)));
typedef float floatx4 __attribute__((ext_vector_type(4)));

// ---- async global->LDS, 16B per lane (dest = wave-uniform base + lane*16) ----
typedef const __attribute__((address_space(1))) unsigned int* gas_ptr;
typedef __attribute__((address_space(3))) unsigned int* las_ptr;
__device__ __forceinline__ void gld_lds16(const void* g, void* l) {
  __builtin_amdgcn_global_load_lds((gas_ptr)g, (las_ptr)l, 16, 0, 0);
}

// ---------------- weight prep: cvt+transpose W[k][n] fp32 -> Wt[n][k] f16 ----------------
__global__ __launch_bounds__(256)
void prep_w_kernel(const float* __restrict__ Wq, const float* __restrict__ Wk,
                   const float* __restrict__ Wv, const float* __restrict__ Wo,
                   _Float16* __restrict__ Tq, _Float16* __restrict__ Tk,
                   _Float16* __restrict__ Tv, _Float16* __restrict__ To) {
  __shared__ float t[64][65];
  int b = blockIdx.x;
  int z = b / 144, rem = b % 144;
  const float* W = z == 0 ? Wq : z == 1 ? Wk : z == 2 ? Wv : Wo;
  _Float16* T = z == 0 ? Tq : z == 1 ? Tk : z == 2 ? Tv : To;
  int n0 = (rem % 12) * 64, k0 = (rem / 12) * 64;
  int tx = threadIdx.x & 15, ty = threadIdx.x >> 4;
#pragma unroll
  for (int i = 0; i < 4; ++i) {
    int row = ty + i * 16;
    float4 v = *(const float4*)(W + (size_t)(k0 + row) * DM + n0 + tx * 4);
    t[row][tx * 4 + 0] = v.x; t[row][tx * 4 + 1] = v.y;
    t[row][tx * 4 + 2] = v.z; t[row][tx * 4 + 3] = v.w;
  }
  __syncthreads();
#pragma unroll
  for (int i = 0; i < 4; ++i) {
    int nn = ty + i * 16, kk = tx * 4;
    half4_t h = {(_Float16)t[kk + 0][nn], (_Float16)t[kk + 1][nn],
                 (_Float16)t[kk + 2][nn], (_Float16)t[kk + 3][nn]};
    *(half4_t*)(T + (size_t)(n0 + nn) * DM + k0 + kk) = h;
  }
}

// ---------------- QKV GEMM: 64x128 tile, fp32 A padded-LDS async, f16 B ----------------
// BN=128 halves A-staging traffic (the dominant term: A fp32 staged by N/BN blocks).
// 576 blocks = 8 XCDs x 12 (z,m)-panels x 6 n-tiles. 33.4 KB LDS -> 4 blocks/CU.
#define GBM 64
#define GBN 128
#define GBK 64
#define ACH 17  // A chunks per row incl. 1 pad slot (row bank-shift 4 -> 2-way, free)

__global__ __launch_bounds__(256, 4)
void gemm_qkv_kernel(const float* __restrict__ A0, const float* __restrict__ A1,
                     const float* __restrict__ A2, const _Float16* __restrict__ W0,
                     const _Float16* __restrict__ W1, const _Float16* __restrict__ W2,
                     const float* __restrict__ b0, const float* __restrict__ b1,
                     const float* __restrict__ b2, _Float16* __restrict__ Q,
                     _Float16* __restrict__ K, _Float16* __restrict__ Vt) {
  __shared__ __align__(16) float Asf[GBM * ACH * 4];   // 17 KB fp32, padded
  __shared__ __align__(16) _Float16 Bs[GBN * GBK];     // 16 KB
  // 576 blocks = 8 XCDs x 12 panels x 6 n-tiles
  const int bid = blockIdx.x;
  const int xcd = bid & 7;
  const int li = bid >> 3;               // 0..71
  const int panel = xcd * 12 + li / 6;   // 0..95 = z*32 + m-block
  const int nb = li % 6;
  const int z = panel >> 5;
  const int m0 = (panel & 31) * GBM;
  const int n0 = nb * GBN;
  const float* A = z == 0 ? A0 : z == 1 ? A1 : A2;
  const _Float16* Wt = z == 0 ? W0 : z == 1 ? W1 : W2;
  const float* bias = z == 0 ? b0 : z == 1 ? b1 : b2;

  const int tid = threadIdx.x;
  const int lane = tid & 63;
  const int w = tid >> 6;
  const int lr = lane & 15;
  const int lq = lane >> 4;
  const int wm = w >> 1, wn = w & 1;   // 2x2 waves; wave tile 32x64
  const int wb = tid & 192;

  floatx4 acc[2][4] = {};

  for (int k0 = 0; k0 < DM; k0 += GBK) {
    __syncthreads();
    // A: 64 rows x 17 slots = 1088 (slot 16 = dup of chunk 15, never read)
#pragma unroll
    for (int i = 0; i < 5; ++i) {
      if (i < 4 || tid < 64) {  // wave-uniform tail
        int s = i * 256 + tid;
        int m = s / ACH, pos = s % ACH;
        int ch = pos < 16 ? pos : 15;
        gld_lds16(A + (size_t)(m0 + m) * DM + k0 + ch * 4, &Asf[(i * 256 + wb) * 4]);
      }
    }
    // B: 128 rows x 8 f16-chunks = 1024, XOR swizzle (2-way, free)
#pragma unroll
    for (int i = 0; i < 4; ++i) {
      int c = i * 256 + tid;
      int n = c >> 3, j = c & 7, jg = j ^ (n & 7);
      gld_lds16(Wt + (size_t)(n0 + n) * DM + k0 + jg * 8, &Bs[(i * 256 + wb) * 8]);
    }
    __syncthreads();  // vmcnt drain -> staged data visible

#pragma unroll
    for (int kh = 0; kh < 2; ++kh) {
      half8 af[2], bf[4];
#pragma unroll
      for (int mt = 0; mt < 2; ++mt) {
        int m = wm * 32 + mt * 16 + lr;
        int j0 = kh * 8 + lq * 2;  // no swizzle: padding staggers banks
        float4 f0 = *(const float4*)&Asf[(m * ACH + j0) * 4];
        float4 f1 = *(const float4*)&Asf[(m * ACH + j0 + 1) * 4];
        af[mt] = half8{(_Float16)f0.x, (_Float16)f0.y, (_Float16)f0.z, (_Float16)f0.w,
                       (_Float16)f1.x, (_Float16)f1.y, (_Float16)f1.z, (_Float16)f1.w};
      }
#pragma unroll
      for (int nt = 0; nt < 4; ++nt) {
        int n = wn * 64 + nt * 16 + lr;
        int j = (kh * 4 + lq) ^ (n & 7);
        bf[nt] = *(const half8*)&Bs[n * GBK + j * 8];
      }
#pragma unroll
      for (int mt = 0; mt < 2; ++mt)
#pragma unroll
        for (int nt = 0; nt < 4; ++nt)
          acc[mt][nt] = __builtin_amdgcn_mfma_f32_16x16x32_f16(af[mt], bf[nt], acc[mt][nt], 0, 0, 0);
    }
  }

#pragma unroll
  for (int mt = 0; mt < 2; ++mt) {
    int row0 = m0 + wm * 32 + mt * 16 + lq * 4;
#pragma unroll
    for (int nt = 0; nt < 4; ++nt) {
      int col = n0 + wn * 64 + nt * 16 + lr;
      float bv = bias[col];
      if (z == 2) {  // V proj: write V^T[d=col][s=row] (fused transpose)
        half4_t o = {(_Float16)(acc[mt][nt][0] + bv), (_Float16)(acc[mt][nt][1] + bv),
                     (_Float16)(acc[mt][nt][2] + bv), (_Float16)(acc[mt][nt][3] + bv)};
        *(half4_t*)(Vt + (size_t)col * S_LEN + row0) = o;
      } else {
        _Float16* H = z == 0 ? Q : K;
#pragma unroll
        for (int rr = 0; rr < 4; ++rr)
          H[(size_t)(row0 + rr) * DM + col] = (_Float16)(acc[mt][nt][rr] + bv);
      }
    }
  }
}

// ---------------- Wo GEMM (R10): 64x64, f16 A staged async, fp32 out ----------------
#define OBM 64
#define OBN 64

__global__ __launch_bounds__(256, 6)
void gemm_out_kernel(const _Float16* __restrict__ A, const _Float16* __restrict__ Wt,
                     const float* __restrict__ bias, float* __restrict__ C) {
  __shared__ __align__(16) _Float16 As[OBM * GBK];
  __shared__ __align__(16) _Float16 Bs[OBN * GBK];
  // 384 blocks = 8 XCDs x 4 m-panels x 12 n-tiles
  const int bid = blockIdx.x;
  const int xcd = bid & 7;
  const int li = bid >> 3;
  const int m0 = (xcd * 4 + li / 12) * OBM;
  const int n0 = (li % 12) * OBN;
  const int tid = threadIdx.x;
  const int lane = tid & 63;
  const int w = tid >> 6;
  const int lr = lane & 15;
  const int lq = lane >> 4;
  const int wm = w >> 1, wn = w & 1;
  const int wb = tid & 192;

  floatx4 acc[2][2] = {};

  for (int k0 = 0; k0 < DM; k0 += GBK) {
    __syncthreads();
#pragma unroll
    for (int i = 0; i < 2; ++i) {
      int c = i * 256 + tid;
      int m = c >> 3, j = c & 7, jg = j ^ (m & 7);
      gld_lds16(A + (size_t)(m0 + m) * DM + k0 + jg * 8, &As[(i * 256 + wb) * 8]);
    }
#pragma unroll
    for (int i = 0; i < 2; ++i) {
      int c = i * 256 + tid;
      int n = c >> 3, j = c & 7, jg = j ^ (n & 7);
      gld_lds16(Wt + (size_t)(n0 + n) * DM + k0 + jg * 8, &Bs[(i * 256 + wb) * 8]);
    }
    __syncthreads();

#pragma unroll
    for (int kh = 0; kh < 2; ++kh) {
      half8 af[2], bf[2];
#pragma unroll
      for (int mt = 0; mt < 2; ++mt) {
        int m = wm * 32 + mt * 16 + lr;
        int j = (kh * 4 + lq) ^ (m & 7);
        af[mt] = *(const half8*)&As[m * GBK + j * 8];
      }
#pragma unroll
      for (int nt = 0; nt < 2; ++nt) {
        int n = wn * 32 + nt * 16 + lr;
        int j = (kh * 4 + lq) ^ (n & 7);
        bf[nt] = *(const half8*)&Bs[n * GBK + j * 8];
      }
#pragma unroll
      for (int mt = 0; mt < 2; ++mt)
#pragma unroll
        for (int nt = 0; nt < 2; ++nt)
          acc[mt][nt] = __builtin_amdgcn_mfma_f32_16x16x32_f16(af[mt], bf[nt], acc[mt][nt], 0, 0, 0);
    }
  }

#pragma unroll
  for (int mt = 0; mt < 2; ++mt) {
    int row0 = m0 + wm * 32 + mt * 16 + lq * 4;
#pragma unroll
    for (int nt = 0; nt < 2; ++nt) {
      int col = n0 + wn * 32 + nt * 16 + lr;
      float bv = bias[col];
#pragma unroll
      for (int rr = 0; rr < 4; ++rr)
        C[(size_t)(row0 + rr) * DM + col] = acc[mt][nt][rr] + bv;
    }
  }
}

// ---------------- MFMA sliding-window attention, in-register softmax (R10) ----------------
#define ATQ 32

__global__ __launch_bounds__(256, 3)
void swattn_mfma_kernel(const _Float16* __restrict__ qh, const _Float16* __restrict__ kh,
                        const _Float16* __restrict__ vt, _Float16* __restrict__ ctx) {
  __shared__ __align__(16) _Float16 Ks[160 * 64];   // 20 KB
  __shared__ __align__(16) _Float16 Vs[64 * 168];   // 21 KB
  __shared__ __align__(16) _Float16 QP[32 * 168];   // 10.5 KB: Qs then Pbuf
  __shared__ float red[4][32];

  const int tid = threadIdx.x;
  const int lane = tid & 63, w = tid >> 6;
  const int lr = lane & 15, lq = lane >> 4;
  const int bid = blockIdx.x;
  const int x = bid & 7, mid = (bid >> 3) & 7, h = bid >> 6;
  const int s0 = (x * 8 + mid) * ATQ;
  const int wb = tid & 192;

  {
    int r = tid >> 3, j = tid & 7, jg = j ^ (r & 7);
    gld_lds16(qh + (size_t)(s0 + r) * DM + h * DHEAD + jg * 8, &QP[wb * 8]);
  }
#pragma unroll
  for (int i = 0; i < 5; ++i) {
    int c = i * 256 + tid;
    int r = c >> 3, j = c & 7, jg = j ^ (r & 7);
    int pos = s0 - HALF_W + r;
    pos = pos < 0 ? 0 : (pos > S_LEN - 1 ? S_LEN - 1 : pos);
    gld_lds16(kh + (size_t)pos * DM + h * DHEAD + jg * 8, &Ks[(i * 256 + wb) * 8]);
  }
#pragma unroll
  for (int i = 0; i < 6; ++i) {
    int c = i * 256 + tid;
    if (c < 1344) {
      int r = c / 21, j = c % 21;
      int cb = s0 - HALF_W + j * 8;
      cb = cb < 0 ? 0 : (cb > S_LEN - 8 ? S_LEN - 8 : cb);
      gld_lds16(vt + (size_t)(h * DHEAD + r) * S_LEN + cb, &Vs[(i * 256 + wb) * 8]);
    }
  }
  __syncthreads();

  const int qt = w & 1, ph = w >> 1;
  floatx4 sc[5];
  {
    half8 aq[2];
#pragma unroll
    for (int k2 = 0; k2 < 2; ++k2) {
      int r = qt * 16 + lr, j = (k2 * 4 + lq) ^ (r & 7);
      aq[k2] = *(const half8*)&QP[r * DHEAD + j * 8];
    }
#pragma unroll
    for (int t = 0; t < 5; ++t) {
      int pt = ph * 5 + t;
      floatx4 a = {};
#pragma unroll
      for (int k2 = 0; k2 < 2; ++k2) {
        int r = pt * 16 + lr, j = (k2 * 4 + lq) ^ (r & 7);
        half8 bk = *(const half8*)&Ks[r * DHEAD + j * 8];
        a = __builtin_amdgcn_mfma_f32_16x16x32_f16(aq[k2], bk, a, 0, 0, 0);
      }
      sc[t] = a;
    }
  }

  const int qbase = qt * 16 + lq * 4;
  float m4[4] = {-1e30f, -1e30f, -1e30f, -1e30f};
#pragma unroll
  for (int t = 0; t < 5; ++t) {
    int p = (ph * 5 + t) * 16 + lr;
    int g = s0 - HALF_W + p;
#pragma unroll
    for (int rr = 0; rr < 4; ++rr) {
      int q = qbase + rr;
      bool ok = (p >= q) && (p <= q + 128) && (g >= 0) && (g < S_LEN);
      float v = ok ? sc[t][rr] * 0.125f : -1e30f;
      sc[t][rr] = v;
      m4[rr] = fmaxf(m4[rr], v);
    }
  }
#pragma unroll
  for (int off = 1; off <= 8; off <<= 1)
#pragma unroll
    for (int rr = 0; rr < 4; ++rr) m4[rr] = fmaxf(m4[rr], __shfl_xor(m4[rr], off, 64));
  if (lr == 0)
#pragma unroll
    for (int rr = 0; rr < 4; ++rr) red[ph][qbase + rr] = m4[rr];
  __syncthreads();

  float ss[4] = {0.f, 0.f, 0.f, 0.f};
  float mm[4];
#pragma unroll
  for (int rr = 0; rr < 4; ++rr)
    mm[rr] = fmaxf(red[0][qbase + rr], red[1][qbase + rr]);
#pragma unroll
  for (int t = 0; t < 5; ++t)
#pragma unroll
    for (int rr = 0; rr < 4; ++rr) {
      float e = __expf(sc[t][rr] - mm[rr]);
      sc[t][rr] = e;
      ss[rr] += e;
    }
#pragma unroll
  for (int off = 1; off <= 8; off <<= 1)
#pragma unroll
    for (int rr = 0; rr < 4; ++rr) ss[rr] += __shfl_xor(ss[rr], off, 64);
  if (lr == 0)
#pragma unroll
    for (int rr = 0; rr < 4; ++rr) red[2 + ph][qbase + rr] = ss[rr];
  __syncthreads();

#pragma unroll
  for (int rr = 0; rr < 4; ++rr) {
    float inv = 1.f / (red[2][qbase + rr] + red[3][qbase + rr]);
#pragma unroll
    for (int t = 0; t < 5; ++t) {
      int p = (ph * 5 + t) * 16 + lr;
      QP[(qbase + rr) * 168 + p] = (_Float16)(sc[t][rr] * inv);
    }
  }
  __syncthreads();

  {
    const int qt2 = w & 1;
    const int dt0 = (w >> 1) * 2;
    floatx4 a0 = {}, a1 = {};
#pragma unroll
    for (int ks = 0; ks < 5; ++ks) {
      half8 ap = *(const half8*)&QP[(qt2 * 16 + lr) * 168 + ks * 32 + lq * 8];
      half8 bv0 = *(const half8*)&Vs[(dt0 * 16 + lr) * 168 + ks * 32 + lq * 8];
      half8 bv1 = *(const half8*)&Vs[((dt0 + 1) * 16 + lr) * 168 + ks * 32 + lq * 8];
      a0 = __builtin_amdgcn_mfma_f32_16x16x32_f16(ap, bv0, a0, 0, 0, 0);
      a1 = __builtin_amdgcn_mfma_f32_16x16x32_f16(ap, bv1, a1, 0, 0, 0);
    }
#pragma unroll
    for (int rr = 0; rr < 4; ++rr) {
      size_t row = (size_t)(s0 + qt2 * 16 + lq * 4 + rr) * DM + h * DHEAD;
      ctx[row + dt0 * 16 + lr] = (_Float16)a0[rr];
      ctx[row + (dt0 + 1) * 16 + lr] = (_Float16)a1[rr];
    }
  }
}

// ---------------- launch ----------------
extern "C" void kernel_launch(void* const* d_in, const int* in_sizes, int n_in,
                              void* d_out, int out_size, void* d_ws, size_t ws_size,
                              hipStream_t stream) {
  const float* query = (const float*)d_in[0];
  const float* key   = (const float*)d_in[1];
  const float* value = (const float*)d_in[2];
  const float* Wq = (const float*)d_in[3];
  const float* bq = (const float*)d_in[4];
  const float* Wk = (const float*)d_in[5];
  const float* bk = (const float*)d_in[6];
  const float* Wv = (const float*)d_in[7];
  const float* bv = (const float*)d_in[8];
  const float* Wo = (const float*)d_in[9];
  const float* bo = (const float*)d_in[10];
  float* out = (float*)d_out;

  const size_t nel = (size_t)S_LEN * DM;
  const size_t wel = (size_t)DM * DM;
  _Float16* Wtq = (_Float16*)d_ws;
  _Float16* Wtk = Wtq + wel;
  _Float16* Wtv = Wtk + wel;
  _Float16* Wto = Wtv + wel;
  _Float16* qh = Wto + wel;
  _Float16* khb = qh + nel;
  _Float16* Vtg = khb + nel;   // [768][2048] f16
  _Float16* ctxh = Vtg + nel;

  prep_w_kernel<<<dim3(576), 256, 0, stream>>>(Wq, Wk, Wv, Wo, Wtq, Wtk, Wtv, Wto);
  gemm_qkv_kernel<<<dim3(576), 256, 0, stream>>>(
      query, key, value, Wtq, Wtk, Wtv, bq, bk, bv, qh, khb, Vtg);
  swattn_mfma_kernel<<<dim3((S_LEN / ATQ) * NHEAD), 256, 0, stream>>>(qh, khb, Vtg, ctxh);
  gemm_out_kernel<<<dim3(384), 256, 0, stream>>>(ctxh, Wto, bo, out);
}